// Round 6
// baseline (1946.523 us; speedup 1.0000x reference)
//
#include <hip/hip_runtime.h>
#include <stdint.h>

#define DEV __device__ __forceinline__

using f32x4  = __attribute__((ext_vector_type(4))) float;
using bf16x8 = __attribute__((ext_vector_type(8))) short;
typedef unsigned short u16;
typedef unsigned int   u32;

typedef const __attribute__((address_space(1))) void* gptr_t;
typedef __attribute__((address_space(3))) void*       lptr_t;

DEV u16 f2bf(float f) {               // RTNE float -> bf16 bits
  union { float f; u32 u; } v; v.f = f;
  u32 lsb = (v.u >> 16) & 1u;
  v.u += 0x7fffu + lsb;
  return (u16)(v.u >> 16);
}
DEV float bf2f(u16 h) {
  union { u32 u; float f; } v; v.u = ((u32)h) << 16;
  return v.f;
}
DEV void async16(void* lds, const void* g) {
  __builtin_amdgcn_global_load_lds((gptr_t)(uintptr_t)g,
                                   (lptr_t)(u32)(uintptr_t)lds, 16, 0, 0);
}
// monotone float->uint key (ascending order preserved)
DEV u32 fkey(float v) {
  u32 u = __float_as_uint(v);
  return u ^ ((u & 0x80000000u) ? 0xFFFFFFFFu : 0x80000000u);
}

// ---------------- split kernel: fp32 -> bf16 ----------------
__global__ __launch_bounds__(256) void split1_kernel(const float* __restrict__ src,
                                                     u16* __restrict__ hi, int n) {
  int i = blockIdx.x * 256 + threadIdx.x;
  if (i >= n) return;
  hi[i] = f2bf(src[i]);
}

// ---------------- numpy-replica z kernel ----------------
// zrep[row][ch] = bit-exact replica of np.einsum('btd,fd->btf') fp32 inner dot:
// sum_of_products_contig_outstride0_two, baseline SSE (128-bit, no FMA):
//   4 lanes l (j === l mod 4); per 16-elem block, reversed chain:
//     vac_l = x[j+l]*w[j+l] + (x[j+4+l]*w[j+4+l] + (x[j+8+l]*w[j+8+l] +
//             (x[j+12+l]*w[j+12+l] + vac_l)))        (each step: mul, then add)
//   final: SSE3 hadd -> (v0+v1)+(v2+v3). 1024 = 64 blocks, no tail.
// Block: 256 threads x 2 channels = 512 channels, 16 rows.
__global__ __launch_bounds__(256) void replica_kernel(
    const float* __restrict__ x, const float* __restrict__ W1,
    float* __restrict__ zrep)
{
  __shared__ float xs[16][256];        // 16 rows x 256-k chunk (16 KB)
  const int tid = threadIdx.x;
  const int r0 = blockIdx.y * 16;
  const int c  = blockIdx.x * 512 + tid * 2;

  float vac[16][2][4];
#pragma unroll
  for (int r = 0; r < 16; ++r)
#pragma unroll
    for (int q = 0; q < 2; ++q)
#pragma unroll
      for (int l = 0; l < 4; ++l) vac[r][q][l] = 0.f;

  for (int kc = 0; kc < 1024; kc += 256) {
    __syncthreads();
    // stage x tile: 16 rows x 256 floats = 1024 float4 slots, 4 per thread
#pragma unroll
    for (int i = 0; i < 4; ++i) {
      const int slot = i * 256 + tid;
      const int rr = slot >> 6, cc = slot & 63;
      *(float4*)&xs[rr][cc * 4] =
          *(const float4*)&x[(size_t)(r0 + rr) * 1024 + kc + cc * 4];
    }
    __syncthreads();

    for (int b = 0; b < 16; ++b) {     // 16-element blocks within chunk
      float w0[16], w1[16];
#pragma unroll
      for (int i = 0; i < 4; ++i) {
        *(float4*)&w0[i * 4] = *(const float4*)&W1[(size_t)c * 1024 + kc + b * 16 + i * 4];
        *(float4*)&w1[i * 4] = *(const float4*)&W1[(size_t)(c + 1) * 1024 + kc + b * 16 + i * 4];
      }
#pragma unroll
      for (int r = 0; r < 16; ++r) {
        float xv[16];
#pragma unroll
        for (int i = 0; i < 4; ++i)
          *(float4*)&xv[i * 4] = *(const float4*)&xs[r][b * 16 + i * 4];
#pragma unroll
        for (int l = 0; l < 4; ++l) {
          float t;
          t = __fadd_rn(__fmul_rn(xv[12 + l], w0[12 + l]), vac[r][0][l]);
          t = __fadd_rn(__fmul_rn(xv[ 8 + l], w0[ 8 + l]), t);
          t = __fadd_rn(__fmul_rn(xv[ 4 + l], w0[ 4 + l]), t);
          vac[r][0][l] = __fadd_rn(__fmul_rn(xv[l], w0[l]), t);
          t = __fadd_rn(__fmul_rn(xv[12 + l], w1[12 + l]), vac[r][1][l]);
          t = __fadd_rn(__fmul_rn(xv[ 8 + l], w1[ 8 + l]), t);
          t = __fadd_rn(__fmul_rn(xv[ 4 + l], w1[ 4 + l]), t);
          vac[r][1][l] = __fadd_rn(__fmul_rn(xv[l], w1[l]), t);
        }
      }
    }
  }
#pragma unroll
  for (int r = 0; r < 16; ++r) {
    const float z0 = __fadd_rn(__fadd_rn(vac[r][0][0], vac[r][0][1]),
                               __fadd_rn(vac[r][0][2], vac[r][0][3]));
    const float z1 = __fadd_rn(__fadd_rn(vac[r][1][0], vac[r][1][1]),
                               __fadd_rn(vac[r][1][2], vac[r][1][3]));
    zrep[(size_t)(r0 + r) * 4096 + c]     = z0;
    zrep[(size_t)(r0 + r) * 4096 + c + 1] = z1;
  }
}

// ------- GEMM: C[M,N] = A[M,K] * B[N,K]^T (bf16 operands, B^T layout), fp32 out -------
// 128x128 tile, 256 threads = 4 waves (2x2), each wave 64x64 via 4x4 16x16x32 MFMA frags
template<int BK>
__global__ __launch_bounds__(256) void gemm_bt(
    const u16* __restrict__ A, const u16* __restrict__ B,
    float* __restrict__ C, int N, int K)
{
  constexpr int TILE = 128 * BK;
  __shared__ u16 smem[2 * TILE];
  u16* sA = smem;
  u16* sB = smem + TILE;

  const int tid  = threadIdx.x;
  const int lane = tid & 63;
  const int wave = tid >> 6;
  const int wr = wave >> 1, wc = wave & 1;
  const int m0 = blockIdx.y * 128, n0 = blockIdx.x * 128;

  f32x4 acc[4][4] = {};

  constexpr int SPR   = BK / 8;
  constexpr int ITERS = (128 * SPR) / 256;

  for (int k0 = 0; k0 < K; k0 += BK) {
#pragma unroll
    for (int i = 0; i < ITERS; ++i) {
      const int slot = i * 256 + tid;
      const int r = slot / SPR, cc = slot % SPR;
      const int uni = (i * 256 + wave * 64) * 8;
      async16(sA + uni, A + (size_t)(m0 + r) * K + k0 + cc * 8);
      async16(sB + uni, B + (size_t)(n0 + r) * K + k0 + cc * 8);
    }
    __syncthreads();

#pragma unroll
    for (int ks = 0; ks < BK / 32; ++ks) {
      const int kb = ks * 32 + (lane >> 4) * 8;
      bf16x8 a[4], b[4];
#pragma unroll
      for (int i = 0; i < 4; ++i) {
        a[i] = *(const bf16x8*)&sA[(wr * 64 + i * 16 + (lane & 15)) * BK + kb];
        b[i] = *(const bf16x8*)&sB[(wc * 64 + i * 16 + (lane & 15)) * BK + kb];
      }
#pragma unroll
      for (int mi = 0; mi < 4; ++mi)
#pragma unroll
        for (int ni = 0; ni < 4; ++ni)
          acc[mi][ni] = __builtin_amdgcn_mfma_f32_16x16x32_bf16(a[mi], b[ni], acc[mi][ni], 0, 0, 0);
    }
    __syncthreads();
  }

#pragma unroll
  for (int mi = 0; mi < 4; ++mi) {
    const int rbase = m0 + wr * 64 + mi * 16 + (lane >> 4) * 4;
#pragma unroll
    for (int ni = 0; ni < 4; ++ni) {
      const int col = n0 + wc * 64 + ni * 16 + (lane & 15);
#pragma unroll
      for (int r2 = 0; r2 < 4; ++r2)
        C[(size_t)(rbase + r2) * N + col] = acc[mi][ni][r2];
    }
  }
}

// ---------------- per-row top-k on replica act keys + s build ----------------
// key = fp32-quantized silu(zrep) (monotone in z, collapses near-ties like the
// reference's fp32 act comparison). Radix-selects the k-th largest key exactly;
// all keys > kth selected; ties at kth filled in ascending index order (stable).
__global__ __launch_bounds__(256) void select2_kernel(
    const float* __restrict__ zrep, const float* __restrict__ g,
    u16* __restrict__ sbuf, const int* __restrict__ kptr)
{
  const int DFF = 4096;
  const int row = blockIdx.x, tid = threadIdx.x;
  const int k = *kptr;

  __shared__ u32 keys[4096];
  __shared__ float acts[4096];
  __shared__ u32 hist[256];
  __shared__ u32 s_bin, s_kk;
  __shared__ int tie_idx[64];
  __shared__ int s_T;
  __shared__ unsigned char tie_sel[64];

  const float* zr = zrep + (size_t)row * DFF;
  for (int f = tid; f < DFF; f += 256) {
    const double zd = (double)zr[f];
    const float act = (float)(zd / (1.0 + exp(-zd)));
    acts[f] = act;
    keys[f] = fkey(act);
  }
  __syncthreads();

  // radix select the k-th largest key
  u32 prefix = 0, kk = (u32)k;
  for (int sh = 24; sh >= 0; sh -= 8) {
    hist[tid] = 0;
    __syncthreads();
    const u32 maskhi = (sh == 24) ? 0u : (0xFFFFFFFFu << (sh + 8));
    for (int f = tid; f < DFF; f += 256) {
      const u32 u = keys[f];
      if ((u & maskhi) == prefix) atomicAdd(&hist[(u >> sh) & 255], 1u);
    }
    __syncthreads();
    if (tid == 0) {
      u32 cum = 0;
      for (int b = 255; b >= 0; --b) {
        const u32 cnt = hist[b];
        if (cum + cnt >= kk) { s_bin = (u32)b; s_kk = kk - cum; break; }
        cum += cnt;
      }
    }
    __syncthreads();
    prefix |= (s_bin << sh);
    kk = s_kk;
    __syncthreads();
  }
  const u32 kth = prefix;          // k-th largest key
  const int take_ties = (int)kk;   // how many key==kth to include

  // collect tie indices
  if (tid == 0) s_T = 0;
  __syncthreads();
  for (int f = tid; f < DFF; f += 256) {
    if (keys[f] == kth) {
      const int p = atomicAdd(&s_T, 1);
      if (p < 64) tie_idx[p] = f;
    }
  }
  __syncthreads();
  const int T = s_T;

  if (T <= 64) {
    // mark the `take_ties` lowest-index ties (stable top_k semantics)
    if (tid == 0) {
      for (int i = 0; i < T; ++i) tie_sel[i] = 0;
      for (int t = 0; t < take_ties; ++t) {
        int best = -1;
        for (int i = 0; i < T; ++i)
          if (!tie_sel[i] && (best < 0 || tie_idx[i] < tie_idx[best])) best = i;
        if (best >= 0) tie_sel[best] = 1;
      }
    }
    __syncthreads();
    const float* grow = g + (size_t)row * DFF;
    for (int f = tid; f < DFF; f += 256) {
      const u32 u = keys[f];
      bool sel = (u > kth);
      if (!sel && u == kth) {
        for (int i = 0; i < T; ++i)
          if (tie_idx[i] == f) { sel = (tie_sel[i] != 0); break; }
      }
      const float sval = sel ? acts[f] * grow[f] : 0.f;
      sbuf[(size_t)row * DFF + f] = f2bf(sval);
    }
  } else {
    // freak case (>64 bitwise-equal keys at boundary): serial stable fill
    if (tid == 0) {
      int cnt = 0;
      for (int f = 0; f < DFF; ++f) if (keys[f] > kth) ++cnt;
      const float* grow = g + (size_t)row * DFF;
      int taken = 0;
      for (int f = 0; f < DFF; ++f) {
        bool sel = (keys[f] > kth);
        if (!sel && keys[f] == kth && taken < take_ties) { sel = true; ++taken; }
        sbuf[(size_t)row * DFF + f] = f2bf(sel ? acts[f] * grow[f] : 0.f);
      }
      (void)cnt;
    }
  }
}

// ---------------- launch ----------------
extern "C" void kernel_launch(void* const* d_in, const int* in_sizes, int n_in,
                              void* d_out, int out_size, void* d_ws, size_t ws_size,
                              hipStream_t stream)
{
  const float* x  = (const float*)d_in[0];
  const float* W1 = (const float*)d_in[1];
  const float* W2 = (const float*)d_in[2];
  const float* Wo = (const float*)d_in[3];
  const int* kptr = (const int*)d_in[4];

  const int DM = 1024, DF = 4096;
  const int M = in_sizes[0] / DM;   // 8192 rows
  const size_t nX = (size_t)M * DM, nW = (size_t)DF * DM, nWo = (size_t)DM * DF;

  // fixed bf16 buffers (gate/down GEMM operands)
  char* w = (char*)d_ws;
  u16* x_hi  = (u16*)w;  w += nX * 2;
  u16* W2_hi = (u16*)w;  w += nW * 2;
  u16* Wo_hi = (u16*)w;  w += nWo * 2;
  const size_t fixed_bytes = (size_t)(w - (char*)d_ws);

  // per-chunk activations: zrep(4) + g(4) + s(2) = 10 B/elem
  int nch = 1;
  while (nch < 64) {
    const size_t per = (size_t)(M / nch) * DF * 10;
    if (fixed_bytes + per <= ws_size) break;
    nch *= 2;
  }
  const int Mc = M / nch;

  float* zrep = (float*)w;
  float* gbuf = (float*)(w + (size_t)Mc * DF * 4);
  u16*   sbuf = (u16*)(w + (size_t)Mc * DF * 8);

  split1_kernel<<<dim3((int)((nX + 255) / 256)), 256, 0, stream>>>(x, x_hi, (int)nX);
  split1_kernel<<<dim3((int)((nW + 255) / 256)), 256, 0, stream>>>(W2, W2_hi, (int)nW);
  split1_kernel<<<dim3((int)((nWo + 255) / 256)), 256, 0, stream>>>(Wo, Wo_hi, (int)nWo);

  for (int ch = 0; ch < nch; ++ch) {
    const size_t ro = (size_t)ch * Mc;
    // z replica for ALL channels (numpy fp32 einsum bit-replica)
    replica_kernel<<<dim3(DF / 512, Mc / 16), 256, 0, stream>>>(
        x + ro * DM, W1, zrep);
    // gate = x @ W2^T (1-pass bf16, fp32 out)
    gemm_bt<64><<<dim3(DF / 128, Mc / 128), 256, 0, stream>>>(
        x_hi + ro * DM, W2_hi, gbuf, DF, DM);
    // top-k on replica act keys + s build
    select2_kernel<<<dim3(Mc), 256, 0, stream>>>(zrep, gbuf, sbuf, kptr);
    // out = s @ Wo^T (1-pass bf16, fp32 out)
    gemm_bt<64><<<dim3(DM / 128, Mc / 128), 256, 0, stream>>>(
        sbuf, Wo_hi, (float*)d_out + ro * DM, DM, DF);
  }
}